// Round 3
// baseline (2518.926 us; speedup 1.0000x reference)
//
#include <hip/hip_runtime.h>
#include <math.h>

// Problem constants
constexpr int DD    = 512;     // D
constexpr int D2    = 1024;    // 2D
constexpr int NTOK  = 256;     // vocab V (unique tokens = unique pipelines)
constexpr int NSYM  = 512;
constexpr int NCON  = 64;
constexpr int VOCAB = 256;
constexpr int BS_TOT = 32 * 512;   // B*S = 16384
constexpr int NDEPTH = 6;
constexpr int NLOOK  = 3;
constexpr float EPSF = 1e-8f;
constexpr float SCALE = 0.044194173824159216f; // 512^-0.5

// ---------------- init / histogram ----------------
__global__ void zero_kernel(float* symErr, float* conErr, int* hist) {
    int t = threadIdx.x;
    symErr[t] = 0.f; conErr[t] = 0.f; hist[t] = 0;
}

__global__ void hist_kernel(const int* __restrict__ x, int* __restrict__ hist) {
    int i = blockIdx.x * 256 + threadIdx.x;
    atomicAdd(&hist[x[i]], 1);
}

// ---------------- generic 32x32 LDS transpose: out[C][R] = in[R][C] ----------------
// grid (C/32, R/32), block (32,8)
__global__ void transpose_kernel(const float* __restrict__ in, float* __restrict__ out,
                                 int R, int C) {
    __shared__ float t[32][33];
    int c0 = blockIdx.x * 32, r0 = blockIdx.y * 32;
    int x = threadIdx.x, y = threadIdx.y;
#pragma unroll
    for (int i = 0; i < 32; i += 8)
        t[y + i][x] = in[(size_t)(r0 + y + i) * C + c0 + x];
    __syncthreads();
#pragma unroll
    for (int i = 0; i < 32; i += 8)
        out[(size_t)(c0 + y + i) * R + r0 + x] = t[x][y + i];
}

// ---------------- embedding: z = (mag*cos(phase), mag*sin(phase)) ----------------
__global__ void embed_kernel(const float* __restrict__ mag, const float* __restrict__ phase,
                             float* __restrict__ dst) {
    int v = blockIdx.x, j = threadIdx.x;          // block 512
    float r = mag[v * DD + j], t = phase[v * DD + j];
    dst[v * D2 + j]      = r * cosf(t);
    dst[v * D2 + DD + j] = r * sinf(t);
}

// ---------------- sym code norms ----------------
__global__ void symnorm_kernel(const float* __restrict__ sym, float* __restrict__ snorm) {
    int c = blockIdx.x, tid = threadIdx.x;        // block 256
    const float4* r = (const float4*)(sym + (size_t)c * D2);
    float4 v = r[tid];
    float p = v.x*v.x + v.y*v.y + v.z*v.z + v.w*v.w;
    __shared__ float red[256];
    red[tid] = p; __syncthreads();
    for (int off = 128; off > 0; off >>= 1) {
        if (tid < off) red[tid] += red[tid + off];
        __syncthreads();
    }
    if (tid == 0) snorm[c] = red[0];
}

// ---------------- cell (transposed weights, scalar-z): coalesced ----------------
// grid (2, 128): j = bx*256+tid covers 512 outputs; 2 tokens per block via scalar pipe.
__global__ __launch_bounds__(256) void cellT_kernel(const float* __restrict__ src,
                                                    float* __restrict__ dst,
                                                    const float* __restrict__ WrT,
                                                    const float* __restrict__ WiT) {
    int j  = blockIdx.x * 256 + threadIdx.x;
    int t0 = blockIdx.y * 2;
    const float* z0 = src + (size_t)t0 * D2;
    const float* z1 = src + (size_t)(t0 + 1) * D2;
    float ar0 = 0.f, ai0 = 0.f, ar1 = 0.f, ai1 = 0.f;
#pragma unroll 4
    for (int k = 0; k < DD; ++k) {
        float wr = WrT[(size_t)k * DD + j];     // coalesced across lanes
        float wi = WiT[(size_t)k * DD + j];
        float zr0 = z0[k], zi0 = z0[DD + k];    // wave-uniform -> s_load
        float zr1 = z1[k], zi1 = z1[DD + k];
        ar0 += wr * zr0; ar0 -= wi * zi0;
        ai0 += wr * zi0; ai0 += wi * zr0;
        ar1 += wr * zr1; ar1 -= wi * zi1;
        ai1 += wr * zi1; ai1 += wi * zr1;
    }
    {
        float m = sqrtf(ar0*ar0 + ai0*ai0 + EPSF);
        float inv = 1.0f / (1.0f + m);
        dst[(size_t)t0 * D2 + j]      = tanhf(ar0 * inv);
        dst[(size_t)t0 * D2 + DD + j] = tanhf(ai0 * inv);
    }
    {
        float m = sqrtf(ar1*ar1 + ai1*ai1 + EPSF);
        float inv = 1.0f / (1.0f + m);
        dst[(size_t)(t0 + 1) * D2 + j]      = tanhf(ar1 * inv);
        dst[(size_t)(t0 + 1) * D2 + DD + j] = tanhf(ai1 * inv);
    }
}

// ---------------- generic matvec (transposed W, scalar-x): dst[t][j] = WT[:,j]·x[t] + b[j] ----
// grid (out_dim/256, NTOK/2), block 256, 2 tokens per block.
__global__ __launch_bounds__(256) void matvecT_kernel(const float* __restrict__ WT,
                                                      const float* __restrict__ bias,
                                                      const float* __restrict__ src,
                                                      float* __restrict__ dst,
                                                      int in_dim, int out_dim) {
    int j  = blockIdx.x * 256 + threadIdx.x;
    int t0 = blockIdx.y * 2;
    const float* x0 = src + (size_t)t0 * in_dim;
    const float* x1 = src + (size_t)(t0 + 1) * in_dim;
    float a0 = 0.f, a1 = 0.f;
#pragma unroll 4
    for (int k = 0; k < in_dim; ++k) {
        float w = WT[(size_t)k * out_dim + j];  // coalesced
        a0 += w * x0[k];                        // x uniform -> s_load
        a1 += w * x1[k];
    }
    float b = bias[j];
    dst[(size_t)t0 * out_dim + j]       = a0 + b;
    dst[(size_t)(t0 + 1) * out_dim + j] = a1 + b;
}

// ---------------- sym dot matrix: dotb[t][c] = z[t]·sym[c] ----------------
// grid (2, 128), block 256: c = bx*256+tid, 2 tokens per block.
__global__ __launch_bounds__(256) void symdot_kernel(const float* __restrict__ symT,
                                                     const float* __restrict__ z,
                                                     float* __restrict__ dotb) {
    int c  = blockIdx.x * 256 + threadIdx.x;
    int t0 = blockIdx.y * 2;
    const float* z0 = z + (size_t)t0 * D2;
    const float* z1 = z + (size_t)(t0 + 1) * D2;
    float a0 = 0.f, a1 = 0.f;
#pragma unroll 4
    for (int k = 0; k < D2; ++k) {
        float w = symT[(size_t)k * NSYM + c];   // coalesced
        a0 += w * z0[k];
        a1 += w * z1[k];
    }
    dotb[(size_t)t0 * NSYM + c]       = a0;
    dotb[(size_t)(t0 + 1) * NSYM + c] = a1;
}

// ---------------- attend: scores, softmax, ctx update ----------------
// grid 256 (token), block 256. Q precomputed. M = number of memory entries.
__global__ __launch_bounds__(256) void attend_kernel(float* __restrict__ z,
                                                     const float* __restrict__ Q,
                                                     const float* __restrict__ Kmem,
                                                     const float* __restrict__ Vmem,
                                                     const float* __restrict__ conf,
                                                     int M) {
    int v = blockIdx.x, tid = threadIdx.x;
    __shared__ float red[256];
    __shared__ float s_sc[8];
    float q0 = Q[(size_t)v * DD + tid];
    float q1 = Q[(size_t)v * DD + 256 + tid];
    for (int m = 0; m < M; ++m) {
        const float* K = Kmem + (size_t)m * NTOK * DD + (size_t)v * DD;
        red[tid] = q0 * K[tid] + q1 * K[256 + tid];
        __syncthreads();
        for (int off = 128; off > 0; off >>= 1) {
            if (tid < off) red[tid] += red[tid + off];
            __syncthreads();
        }
        if (tid == 0) s_sc[m] = red[0] * SCALE * conf[v];
        __syncthreads();
    }
    if (tid == 0) {
        float mx = s_sc[0];
        for (int m = 1; m < M; ++m) mx = fmaxf(mx, s_sc[m]);
        float w[5], sum = 0.f;
        for (int m = 0; m < M; ++m) { w[m] = expf(s_sc[m] - mx); sum += w[m]; }
        for (int m = 0; m < M; ++m) s_sc[m] = w[m] / sum;
    }
    __syncthreads();
#pragma unroll
    for (int r = 0; r < 4; ++r) {
        int e = r * 256 + tid;
        float ctx = 0.f;
        for (int m = 0; m < M; ++m)
            ctx += s_sc[m] * Vmem[(size_t)m * NTOK * D2 + (size_t)v * D2 + e];
        z[(size_t)v * D2 + e] += 0.1f * ctx;
    }
}

// ---------------- finish: argmin, conf, straight-through update, losses, con quantize ----
// grid 256 (1 token/block), block 512.
__global__ __launch_bounds__(512) void finish_kernel(float* __restrict__ z,
                                                     const float* __restrict__ sym,
                                                     const float* __restrict__ snorm,
                                                     const float* __restrict__ con,
                                                     const float* __restrict__ conT,
                                                     const float* __restrict__ dotb,
                                                     float* __restrict__ conf,
                                                     float* __restrict__ symErr,
                                                     float* __restrict__ conErr) {
    int t0 = blockIdx.x;
    int tid = threadIdx.x;
    __shared__ __align__(16) float s_z[D2];
    __shared__ float s_red[512];
    __shared__ int   s_idx[512];
    __shared__ float s_res[4];
    __shared__ int   s_si[1];
    __shared__ float s_pd[256], s_pc[256];

    if (tid < 256) ((float4*)s_z)[tid] = ((const float4*)(z + (size_t)t0 * D2))[tid];
    __syncthreads();

    // ||z||^2 (pre-update)
    {
        float a = s_z[tid], b = s_z[512 + tid];
        s_red[tid] = a * a + b * b;
        __syncthreads();
        for (int off = 256; off > 0; off >>= 1) {
            if (tid < off) s_red[tid] += s_red[tid + off];
            __syncthreads();
        }
        if (tid == 0) s_res[0] = s_red[0];
        __syncthreads();
    }

    // d = (znorm + cn) - 2*dot ; argmin (first-min tie-break)
    {
        float d = (s_res[0] + snorm[tid]) - 2.f * dotb[(size_t)t0 * NSYM + tid];
        s_red[tid] = d; s_idx[tid] = tid;
        __syncthreads();
        for (int off = 256; off > 0; off >>= 1) {
            if (tid < off) {
                float o = s_red[tid + off]; int oi = s_idx[tid + off];
                if (o < s_red[tid] || (o == s_red[tid] && oi < s_idx[tid])) {
                    s_red[tid] = o; s_idx[tid] = oi;
                }
            }
            __syncthreads();
        }
        if (tid == 0) { s_res[1] = s_red[0]; s_si[0] = s_idx[0]; }
        __syncthreads();
    }

    // conf, straight-through update, symErr (direct form)
    {
        int si = s_si[0];
        if (tid == 0) conf[t0] = 1.0f / (1.0f + s_res[1]);
        const float* crow = sym + (size_t)si * D2;
        float errp = 0.f;
#pragma unroll
        for (int r = 0; r < 2; ++r) {
            int e = r * 512 + tid;
            float zf = s_z[e];
            float diff = crow[e] - zf;
            errp += diff * diff;
            float zn = zf + diff;      // zs = z + (c - z), exact two-op fp
            s_z[e] = zn;
            z[(size_t)t0 * D2 + e] = zn;
        }
        s_red[tid] = errp;
        __syncthreads();
        for (int off = 256; off > 0; off >>= 1) {
            if (tid < off) s_red[tid] += s_red[tid + off];
            __syncthreads();
        }
        if (tid == 0) symErr[t0] += s_red[0];
        __syncthreads();
    }

    // ||zs||^2
    {
        float a = s_z[tid], b = s_z[512 + tid];
        s_red[tid] = a * a + b * b;
        __syncthreads();
        for (int off = 256; off > 0; off >>= 1) {
            if (tid < off) s_red[tid] += s_red[tid + off];
            __syncthreads();
        }
        if (tid == 0) s_res[2] = s_red[0];
        __syncthreads();
    }

    // con partial dots, split-K over 4 waves (coalesced conT reads)
    if (tid < 256) {
        int c = tid & 63, sl = tid >> 6;
        float pd = 0.f, pc = 0.f;
        int k0 = sl * 256;
#pragma unroll 4
        for (int k = k0; k < k0 + 256; ++k) {
            float w = conT[(size_t)k * NCON + c];   // 64 lanes consecutive -> coalesced
            pd += w * s_z[k];                       // broadcast LDS read
            pc += w * w;
        }
        s_pd[tid] = pd; s_pc[tid] = pc;
    }
    __syncthreads();
    if (tid < 64) {
        float dot = ((s_pd[tid] + s_pd[64 + tid]) + s_pd[128 + tid]) + s_pd[192 + tid];
        float cn2 = ((s_pc[tid] + s_pc[64 + tid]) + s_pc[128 + tid]) + s_pc[192 + tid];
        s_red[tid] = (s_res[2] + cn2) - 2.f * dot;
        s_idx[tid] = tid;
    }
    __syncthreads();
    for (int off = 32; off > 0; off >>= 1) {
        if (tid < off) {
            float o = s_red[tid + off]; int oi = s_idx[tid + off];
            if (o < s_red[tid] || (o == s_red[tid] && oi < s_idx[tid])) {
                s_red[tid] = o; s_idx[tid] = oi;
            }
        }
        __syncthreads();
    }
    int ci0 = s_idx[0];
    __syncthreads();

    // conErr (direct form vs zs)
    {
        const float* crow = con + (size_t)ci0 * D2;
        float p = 0.f;
#pragma unroll
        for (int r = 0; r < 2; ++r) {
            int e = r * 512 + tid;
            float diff = crow[e] - s_z[e];
            p += diff * diff;
        }
        s_red[tid] = p;
        __syncthreads();
        for (int off = 256; off > 0; off >>= 1) {
            if (tid < off) s_red[tid] += s_red[tid + off];
            __syncthreads();
        }
        if (tid == 0) conErr[t0] += s_red[0];
        __syncthreads();
    }
}

// ---------------- scatter: out[pos] = rows[x[pos]] ----------------
__global__ __launch_bounds__(256) void scatter_kernel(const int* __restrict__ x,
                                                      const float* __restrict__ rows,
                                                      float* __restrict__ out) {
    int tid = threadIdx.x;
    int pos = blockIdx.x * 4 + (tid >> 6);
    int lane = tid & 63;
    int v = x[pos];
    const float4* r = (const float4*)(rows + (size_t)v * VOCAB);
    ((float4*)(out + (size_t)pos * VOCAB))[lane] = r[lane];
}

// ---------------- losses ----------------
__global__ void loss_kernel(const int* __restrict__ hist,
                            const float* __restrict__ symErr,
                            const float* __restrict__ conErr,
                            float* __restrict__ out) {
    int tid = threadIdx.x;   // 256
    __shared__ double rs[256], rc[256];
    rs[tid] = (double)hist[tid] * (double)symErr[tid];
    rc[tid] = (double)hist[tid] * (double)conErr[tid];
    __syncthreads();
    for (int off = 128; off > 0; off >>= 1) {
        if (tid < off) { rs[tid] += rs[tid + off]; rc[tid] += rc[tid + off]; }
        __syncthreads();
    }
    if (tid == 0) {
        const double denom = (double)BS_TOT * (double)D2;   // 16777216
        out[(size_t)BS_TOT * VOCAB]     = (float)(1.25 * rs[0] / denom);
        out[(size_t)BS_TOT * VOCAB + 1] = (float)(1.25 * rc[0] / denom);
    }
}

// ---------------- host ----------------
extern "C" void kernel_launch(void* const* d_in, const int* in_sizes, int n_in,
                              void* d_out, int out_size, void* d_ws, size_t ws_size,
                              hipStream_t stream) {
    const int*   x     = (const int*)  d_in[0];
    const float* mag   = (const float*)d_in[1];
    const float* phase = (const float*)d_in[2];
    const float* Wr    = (const float*)d_in[3];
    const float* Wi    = (const float*)d_in[4];
    const float* qw    = (const float*)d_in[5];
    const float* qb    = (const float*)d_in[6];
    const float* kw    = (const float*)d_in[7];
    const float* kb    = (const float*)d_in[8];
    const float* vw    = (const float*)d_in[9];
    const float* vb    = (const float*)d_in[10];
    const float* dec_w = (const float*)d_in[11];
    const float* dec_b = (const float*)d_in[12];
    const float* sym   = (const float*)d_in[13];
    const float* con   = (const float*)d_in[14];
    float* out = (float*)d_out;

    // workspace layout (floats); total ~27 MB
    float* ws     = (float*)d_ws;
    float* bufA   = ws;                          // 256*1024
    float* bufB   = bufA + NTOK * D2;
    float* Qbuf   = bufB + NTOK * D2;            // 256*512
    float* Kmem   = Qbuf + NTOK * DD;            // 6*256*512
    float* Vmem   = Kmem + NDEPTH * NTOK * DD;   // 6*256*1024
    float* rows   = Vmem + NDEPTH * NTOK * D2;   // 256*256
    float* dotb   = rows + NTOK * VOCAB;         // 256*512
    float* WrT    = dotb + NTOK * NSYM;          // 512*512
    float* WiT    = WrT + DD * DD;               // 512*512
    float* qwT    = WiT + DD * DD;               // 1024*512
    float* kwT    = qwT + D2 * DD;               // 1024*512
    float* vwT    = kwT + D2 * DD;               // 1024*1024
    float* decT   = vwT + D2 * D2;               // 1024*256
    float* symT   = decT + D2 * VOCAB;           // 1024*512
    float* conT   = symT + D2 * NSYM;            // 1024*64
    float* snorm  = conT + D2 * NCON;            // 512
    float* conf   = snorm + NSYM;                // 256
    float* symErr = conf + NTOK;                 // 256
    float* conErr = symErr + NTOK;               // 256
    int*   hist   = (int*)(conErr + NTOK);       // 256

    dim3 tb(32, 8);
    transpose_kernel<<<dim3(16, 16), tb, 0, stream>>>(Wr,    WrT,  DD, DD);
    transpose_kernel<<<dim3(16, 16), tb, 0, stream>>>(Wi,    WiT,  DD, DD);
    transpose_kernel<<<dim3(32, 16), tb, 0, stream>>>(qw,    qwT,  DD, D2);
    transpose_kernel<<<dim3(32, 16), tb, 0, stream>>>(kw,    kwT,  DD, D2);
    transpose_kernel<<<dim3(32, 32), tb, 0, stream>>>(vw,    vwT,  D2, D2);
    transpose_kernel<<<dim3(32,  8), tb, 0, stream>>>(dec_w, decT, VOCAB, D2);
    transpose_kernel<<<dim3(32, 16), tb, 0, stream>>>(sym,   symT, NSYM, D2);
    transpose_kernel<<<dim3(32,  2), tb, 0, stream>>>(con,   conT, NCON, D2);

    zero_kernel<<<1, 256, 0, stream>>>(symErr, conErr, hist);
    hist_kernel<<<BS_TOT / 256, 256, 0, stream>>>(x, hist);
    symnorm_kernel<<<NSYM, 256, 0, stream>>>(sym, snorm);
    embed_kernel<<<NTOK, 512, 0, stream>>>(mag, phase, bufA);

    float* cur = bufA;
    float* oth = bufB;
    for (int d = 0; d < NDEPTH; ++d) {
        cellT_kernel<<<dim3(2, 128), 256, 0, stream>>>(cur, oth, WrT, WiT);
        { float* t = cur; cur = oth; oth = t; }
        if (d > 0) {
            matvecT_kernel<<<dim3(2, 128), 256, 0, stream>>>(qwT, qb, cur, Qbuf, D2, DD);
            attend_kernel<<<NTOK, 256, 0, stream>>>(cur, Qbuf, Kmem, Vmem, conf, d);
        }
        symdot_kernel<<<dim3(2, 128), 256, 0, stream>>>(symT, cur, dotb);
        finish_kernel<<<NTOK, 512, 0, stream>>>(cur, sym, snorm, con, conT, dotb,
                                                conf, symErr, conErr);
        matvecT_kernel<<<dim3(2, 128), 256, 0, stream>>>(kwT, kb, cur,
                                                         Kmem + (size_t)d * NTOK * DD, D2, DD);
        matvecT_kernel<<<dim3(4, 128), 256, 0, stream>>>(vwT, vb, cur,
                                                         Vmem + (size_t)d * NTOK * D2, D2, D2);
    }
    for (int l = 0; l < NLOOK; ++l) {
        cellT_kernel<<<dim3(2, 128), 256, 0, stream>>>(cur, oth, WrT, WiT);
        { float* t = cur; cur = oth; oth = t; }
    }
    matvecT_kernel<<<dim3(1, 128), 256, 0, stream>>>(decT, dec_b, cur, rows, D2, VOCAB);
    scatter_kernel<<<BS_TOT / 4, 256, 0, stream>>>(x, rows, out);
    loss_kernel<<<1, 256, 0, stream>>>(hist, symErr, conErr, out);
}

// Round 4
// 882.037 us; speedup vs baseline: 2.8558x; 2.8558x over previous
//
#include <hip/hip_runtime.h>
#include <math.h>

// Problem constants
constexpr int DD    = 512;     // D
constexpr int D2    = 1024;    // 2D
constexpr int NTOK  = 256;     // vocab V (unique tokens = unique pipelines)
constexpr int NSYM  = 512;
constexpr int NCON  = 64;
constexpr int VOCAB = 256;
constexpr int BS_TOT = 32 * 512;   // B*S = 16384
constexpr int NDEPTH = 6;
constexpr int NLOOK  = 3;
constexpr int SPLIT  = 4;          // K-split for gemm64
constexpr float EPSF = 1e-8f;
constexpr float SCALE = 0.044194173824159216f; // 512^-0.5

__device__ inline void fma4(float4& a, const float4& w, float s) {
    a.x += w.x * s; a.y += w.y * s; a.z += w.z * s; a.w += w.w * s;
}

// ---------------- init / histogram ----------------
__global__ void zero_kernel(float* symErr, float* conErr, int* hist) {
    int t = threadIdx.x;
    symErr[t] = 0.f; conErr[t] = 0.f; hist[t] = 0;
}

__global__ void hist_kernel(const int* __restrict__ x, int* __restrict__ hist) {
    int i = blockIdx.x * 256 + threadIdx.x;
    atomicAdd(&hist[x[i]], 1);
}

// ---------------- transpose with output stride: out[c*ldo + r] = in[r*C + c] ----------------
// grid (C/32, R/32), block (32,8)
__global__ void transposeS_kernel(const float* __restrict__ in, float* __restrict__ out,
                                  int R, int C, int ldo) {
    __shared__ float t[32][33];
    int c0 = blockIdx.x * 32, r0 = blockIdx.y * 32;
    int x = threadIdx.x, y = threadIdx.y;
#pragma unroll
    for (int i = 0; i < 32; i += 8)
        t[y + i][x] = in[(size_t)(r0 + y + i) * C + c0 + x];
    __syncthreads();
#pragma unroll
    for (int i = 0; i < 32; i += 8)
        out[(size_t)(c0 + y + i) * ldo + r0 + x] = t[x][y + i];
}

// ---------------- build combined cell weight CW[1024][1024] ----------------
// CW[k][j]=Wr[j][k]; CW[k][512+j]=Wi[j][k]; CW[512+k][j]=-Wi[j][k]; CW[512+k][512+j]=Wr[j][k]
// grid (16,16) over (j-tile, k-tile), block (32,8)
__global__ void buildcw_kernel(const float* __restrict__ Wr, const float* __restrict__ Wi,
                               float* __restrict__ CW) {
    __shared__ float tr[32][33], ti[32][33];
    int j0 = blockIdx.x * 32, k0 = blockIdx.y * 32;
    int x = threadIdx.x, y = threadIdx.y;
#pragma unroll
    for (int i = 0; i < 32; i += 8) {
        tr[y + i][x] = Wr[(size_t)(j0 + y + i) * DD + k0 + x];
        ti[y + i][x] = Wi[(size_t)(j0 + y + i) * DD + k0 + x];
    }
    __syncthreads();
#pragma unroll
    for (int i = 0; i < 32; i += 8) {
        float vr = tr[x][y + i];    // Wr[j0+x][k0+y+i]
        float vi = ti[x][y + i];
        int k = k0 + y + i, j = j0 + x;
        CW[(size_t)k * D2 + j]                    = vr;
        CW[(size_t)k * D2 + DD + j]               = vi;
        CW[(size_t)(DD + k) * D2 + j]             = -vi;
        CW[(size_t)(DD + k) * D2 + DD + j]        = vr;
    }
}

// ---------------- embedding ----------------
__global__ void embed_kernel(const float* __restrict__ mag, const float* __restrict__ phase,
                             float* __restrict__ dst) {
    int v = blockIdx.x, j = threadIdx.x;          // block 512
    float r = mag[v * DD + j], t = phase[v * DD + j];
    dst[v * D2 + j]      = r * cosf(t);
    dst[v * D2 + DD + j] = r * sinf(t);
}

// ---------------- sym code norms ----------------
__global__ void symnorm_kernel(const float* __restrict__ sym, float* __restrict__ snorm) {
    int c = blockIdx.x, tid = threadIdx.x;        // block 256
    const float4* r = (const float4*)(sym + (size_t)c * D2);
    float4 v = r[tid];
    float p = v.x*v.x + v.y*v.y + v.z*v.z + v.w*v.w;
    __shared__ float red[256];
    red[tid] = p; __syncthreads();
    for (int off = 128; off > 0; off >>= 1) {
        if (tid < off) red[tid] += red[tid + off];
        __syncthreads();
    }
    if (tid == 0) snorm[c] = red[0];
}

// ---------------- tiled GEMM: P[s][t][j] = sum_{k in slice s} X[t][k]*WT[k][j] ----------------
// X: [256][1024] (t-major). WT: [1024][N] (k-major). P: [SPLIT][256][N].
// grid (N/64, 4, SPLIT), block 256. Tile 64j x 64t, thread 4x4. No bias (consumers add it).
__global__ __launch_bounds__(256) void gemm64_kernel(const float* __restrict__ WT,
                                                     const float* __restrict__ X,
                                                     float* __restrict__ P,
                                                     int N) {
    constexpr int KB = D2 / SPLIT;     // 256 k per block
    constexpr int LDT = 68;            // padded LDS row stride
    __shared__ float sX[32 * LDT];     // [k][t]
    __shared__ float sW[32 * LDT];     // [k][j]

    int tid = threadIdx.x;
    int j0 = blockIdx.x * 64;
    int t0 = blockIdx.y * 64;
    int s  = blockIdx.z;
    int k0 = s * KB;

    int jq = tid & 15;        // 16 j-groups of 4
    int tq = tid >> 4;        // 16 t-groups of 4

    float4 acc0 = {0,0,0,0}, acc1 = {0,0,0,0}, acc2 = {0,0,0,0}, acc3 = {0,0,0,0};

    for (int kc = 0; kc < KB / 32; ++kc) {
        int kbase = k0 + kc * 32;
        __syncthreads();
        // stage X tile (64t x 32k, transposed to [k][t]) and W tile (32k x 64j)
#pragma unroll
        for (int b = 0; b < 2; ++b) {
            int f = tid * 2 + b;
            // X: f in [0,512): t = f>>3 (64 tokens), kq = f&7 (8 float4 along k)
            int t = f >> 3, kq = f & 7;
            float4 v = *(const float4*)&X[(size_t)(t0 + t) * D2 + kbase + kq * 4];
            sX[(kq * 4 + 0) * LDT + t] = v.x;
            sX[(kq * 4 + 1) * LDT + t] = v.y;
            sX[(kq * 4 + 2) * LDT + t] = v.z;
            sX[(kq * 4 + 3) * LDT + t] = v.w;
            // W: k = f>>4 (32 rows), j4 = f&15 (16 float4 along j)
            int kw = f >> 4, j4 = f & 15;
            float4 w = *(const float4*)&WT[(size_t)(kbase + kw) * N + j0 + j4 * 4];
            *(float4*)&sW[kw * LDT + j4 * 4] = w;
        }
        __syncthreads();
#pragma unroll 8
        for (int k = 0; k < 32; ++k) {
            float4 xa = *(const float4*)&sX[k * LDT + tq * 4];
            float4 wb = *(const float4*)&sW[k * LDT + jq * 4];
            fma4(acc0, wb, xa.x);
            fma4(acc1, wb, xa.y);
            fma4(acc2, wb, xa.z);
            fma4(acc3, wb, xa.w);
        }
    }
    size_t base = ((size_t)s * NTOK + (t0 + tq * 4)) * N + j0 + jq * 4;
    *(float4*)&P[base]         = acc0;
    *(float4*)&P[base + N]     = acc1;
    *(float4*)&P[base + 2*N]   = acc2;
    *(float4*)&P[base + 3*N]   = acc3;
}

// ---------------- cell epilogue: sum partials, complex saturating norm + tanh ----------------
// grid (2, 256): j = bx*256+tid in [0,512), t = by
__global__ __launch_bounds__(256) void cellepi_kernel(const float* __restrict__ P,
                                                      float* __restrict__ z) {
    int j = blockIdx.x * 256 + threadIdx.x;
    int t = blockIdx.y;
    size_t idx = (size_t)t * D2 + j;
    float lr = 0.f, li = 0.f;
#pragma unroll
    for (int s = 0; s < SPLIT; ++s) {
        lr += P[((size_t)s * NTOK + t) * D2 + j];
        li += P[((size_t)s * NTOK + t) * D2 + DD + j];
    }
    float m = sqrtf(lr * lr + li * li + EPSF);
    float inv = 1.0f / (1.0f + m);
    z[idx]      = tanhf(lr * inv);
    z[idx + DD] = tanhf(li * inv);
}

// ---------------- KV combine: Kmem/Vmem slot = sum partials + bias ----------------
// grid (6, 256): e = bx*256+tid in [0,1536), t = by
__global__ __launch_bounds__(256) void kvcomb_kernel(const float* __restrict__ P,
                                                     const float* __restrict__ kb,
                                                     const float* __restrict__ vb,
                                                     float* __restrict__ Kslot,
                                                     float* __restrict__ Vslot) {
    int e = blockIdx.x * 256 + threadIdx.x;
    int t = blockIdx.y;
    float v = 0.f;
#pragma unroll
    for (int s = 0; s < SPLIT; ++s)
        v += P[((size_t)s * NTOK + t) * 1536 + e];
    if (e < DD) Kslot[(size_t)t * DD + e]        = v + kb[e];
    else        Vslot[(size_t)t * D2 + (e - DD)] = v + vb[e - DD];
}

// ---------------- dec combine: rows = sum partials + dec_b ----------------
// grid 256, block 256: t = bid, j = tid
__global__ void deccomb_kernel(const float* __restrict__ P, const float* __restrict__ db,
                               float* __restrict__ rows) {
    int t = blockIdx.x, j = threadIdx.x;
    float v = 0.f;
#pragma unroll
    for (int s = 0; s < SPLIT; ++s)
        v += P[((size_t)s * NTOK + t) * VOCAB + j];
    rows[(size_t)t * VOCAB + j] = v + db[j];
}

// ---------------- attend: scores, softmax, ctx update (Q from partials + qb) ----------------
// grid 256 (token), block 256. M = number of memory entries.
__global__ __launch_bounds__(256) void attend_kernel(float* __restrict__ z,
                                                     const float* __restrict__ QP,
                                                     const float* __restrict__ qb,
                                                     const float* __restrict__ Kmem,
                                                     const float* __restrict__ Vmem,
                                                     const float* __restrict__ conf,
                                                     int M) {
    int v = blockIdx.x, tid = threadIdx.x;
    __shared__ float red[256];
    __shared__ float s_sc[8];
    float q0 = 0.f, q1 = 0.f;
#pragma unroll
    for (int s = 0; s < SPLIT; ++s) {
        q0 += QP[((size_t)s * NTOK + v) * DD + tid];
        q1 += QP[((size_t)s * NTOK + v) * DD + 256 + tid];
    }
    q0 += qb[tid];
    q1 += qb[256 + tid];
    for (int m = 0; m < M; ++m) {
        const float* K = Kmem + (size_t)m * NTOK * DD + (size_t)v * DD;
        red[tid] = q0 * K[tid] + q1 * K[256 + tid];
        __syncthreads();
        for (int off = 128; off > 0; off >>= 1) {
            if (tid < off) red[tid] += red[tid + off];
            __syncthreads();
        }
        if (tid == 0) s_sc[m] = red[0] * SCALE * conf[v];
        __syncthreads();
    }
    if (tid == 0) {
        float mx = s_sc[0];
        for (int m = 1; m < M; ++m) mx = fmaxf(mx, s_sc[m]);
        float w[5], sum = 0.f;
        for (int m = 0; m < M; ++m) { w[m] = expf(s_sc[m] - mx); sum += w[m]; }
        for (int m = 0; m < M; ++m) s_sc[m] = w[m] / sum;
    }
    __syncthreads();
#pragma unroll
    for (int r = 0; r < 4; ++r) {
        int e = r * 256 + tid;
        float ctx = 0.f;
        for (int m = 0; m < M; ++m)
            ctx += s_sc[m] * Vmem[(size_t)m * NTOK * D2 + (size_t)v * D2 + e];
        z[(size_t)v * D2 + e] += 0.1f * ctx;
    }
}

// ---------------- finish: argmin, conf, straight-through update, losses, con quantize ----
// grid 256 (1 token/block), block 512. dot from symP partials.
__global__ __launch_bounds__(512) void finish_kernel(float* __restrict__ z,
                                                     const float* __restrict__ sym,
                                                     const float* __restrict__ snorm,
                                                     const float* __restrict__ con,
                                                     const float* __restrict__ conT,
                                                     const float* __restrict__ symP,
                                                     float* __restrict__ conf,
                                                     float* __restrict__ symErr,
                                                     float* __restrict__ conErr) {
    int t0 = blockIdx.x;
    int tid = threadIdx.x;
    __shared__ __align__(16) float s_z[D2];
    __shared__ float s_red[512];
    __shared__ int   s_idx[512];
    __shared__ float s_res[4];
    __shared__ int   s_si[1];
    __shared__ float s_pd[256], s_pc[256];

    if (tid < 256) ((float4*)s_z)[tid] = ((const float4*)(z + (size_t)t0 * D2))[tid];
    __syncthreads();

    // ||z||^2 (pre-update)
    {
        float a = s_z[tid], b = s_z[512 + tid];
        s_red[tid] = a * a + b * b;
        __syncthreads();
        for (int off = 256; off > 0; off >>= 1) {
            if (tid < off) s_red[tid] += s_red[tid + off];
            __syncthreads();
        }
        if (tid == 0) s_res[0] = s_red[0];
        __syncthreads();
    }

    // d = (znorm + cn) - 2*dot ; argmin (first-min tie-break)
    {
        float dot = 0.f;
#pragma unroll
        for (int s = 0; s < SPLIT; ++s)
            dot += symP[((size_t)s * NTOK + t0) * NSYM + tid];
        float d = (s_res[0] + snorm[tid]) - 2.f * dot;
        s_red[tid] = d; s_idx[tid] = tid;
        __syncthreads();
        for (int off = 256; off > 0; off >>= 1) {
            if (tid < off) {
                float o = s_red[tid + off]; int oi = s_idx[tid + off];
                if (o < s_red[tid] || (o == s_red[tid] && oi < s_idx[tid])) {
                    s_red[tid] = o; s_idx[tid] = oi;
                }
            }
            __syncthreads();
        }
        if (tid == 0) { s_res[1] = s_red[0]; s_si[0] = s_idx[0]; }
        __syncthreads();
    }

    // conf, straight-through update, symErr (direct form)
    {
        int si = s_si[0];
        if (tid == 0) conf[t0] = 1.0f / (1.0f + s_res[1]);
        const float* crow = sym + (size_t)si * D2;
        float errp = 0.f;
#pragma unroll
        for (int r = 0; r < 2; ++r) {
            int e = r * 512 + tid;
            float zf = s_z[e];
            float diff = crow[e] - zf;
            errp += diff * diff;
            float zn = zf + diff;      // zs = z + (c - z), exact two-op fp
            s_z[e] = zn;
            z[(size_t)t0 * D2 + e] = zn;
        }
        s_red[tid] = errp;
        __syncthreads();
        for (int off = 256; off > 0; off >>= 1) {
            if (tid < off) s_red[tid] += s_red[tid + off];
            __syncthreads();
        }
        if (tid == 0) symErr[t0] += s_red[0];
        __syncthreads();
    }

    // ||zs||^2
    {
        float a = s_z[tid], b = s_z[512 + tid];
        s_red[tid] = a * a + b * b;
        __syncthreads();
        for (int off = 256; off > 0; off >>= 1) {
            if (tid < off) s_red[tid] += s_red[tid + off];
            __syncthreads();
        }
        if (tid == 0) s_res[2] = s_red[0];
        __syncthreads();
    }

    // con partial dots, split-K over 4 waves (coalesced conT reads)
    if (tid < 256) {
        int c = tid & 63, sl = tid >> 6;
        float pd = 0.f, pc = 0.f;
        int k0 = sl * 256;
#pragma unroll 4
        for (int k = k0; k < k0 + 256; ++k) {
            float w = conT[(size_t)k * NCON + c];
            pd += w * s_z[k];
            pc += w * w;
        }
        s_pd[tid] = pd; s_pc[tid] = pc;
    }
    __syncthreads();
    if (tid < 64) {
        float dot = ((s_pd[tid] + s_pd[64 + tid]) + s_pd[128 + tid]) + s_pd[192 + tid];
        float cn2 = ((s_pc[tid] + s_pc[64 + tid]) + s_pc[128 + tid]) + s_pc[192 + tid];
        s_red[tid] = (s_res[2] + cn2) - 2.f * dot;
        s_idx[tid] = tid;
    }
    __syncthreads();
    for (int off = 32; off > 0; off >>= 1) {
        if (tid < off) {
            float o = s_red[tid + off]; int oi = s_idx[tid + off];
            if (o < s_red[tid] || (o == s_red[tid] && oi < s_idx[tid])) {
                s_red[tid] = o; s_idx[tid] = oi;
            }
        }
        __syncthreads();
    }
    int ci0 = s_idx[0];
    __syncthreads();

    // conErr (direct form vs zs)
    {
        const float* crow = con + (size_t)ci0 * D2;
        float p = 0.f;
#pragma unroll
        for (int r = 0; r < 2; ++r) {
            int e = r * 512 + tid;
            float diff = crow[e] - s_z[e];
            p += diff * diff;
        }
        s_red[tid] = p;
        __syncthreads();
        for (int off = 256; off > 0; off >>= 1) {
            if (tid < off) s_red[tid] += s_red[tid + off];
            __syncthreads();
        }
        if (tid == 0) conErr[t0] += s_red[0];
        __syncthreads();
    }
}

// ---------------- scatter: out[pos] = rows[x[pos]] ----------------
__global__ __launch_bounds__(256) void scatter_kernel(const int* __restrict__ x,
                                                      const float* __restrict__ rows,
                                                      float* __restrict__ out) {
    int tid = threadIdx.x;
    int pos = blockIdx.x * 4 + (tid >> 6);
    int lane = tid & 63;
    int v = x[pos];
    const float4* r = (const float4*)(rows + (size_t)v * VOCAB);
    ((float4*)(out + (size_t)pos * VOCAB))[lane] = r[lane];
}

// ---------------- losses ----------------
__global__ void loss_kernel(const int* __restrict__ hist,
                            const float* __restrict__ symErr,
                            const float* __restrict__ conErr,
                            float* __restrict__ out) {
    int tid = threadIdx.x;   // 256
    __shared__ double rs[256], rc[256];
    rs[tid] = (double)hist[tid] * (double)symErr[tid];
    rc[tid] = (double)hist[tid] * (double)conErr[tid];
    __syncthreads();
    for (int off = 128; off > 0; off >>= 1) {
        if (tid < off) { rs[tid] += rs[tid + off]; rc[tid] += rc[tid + off]; }
        __syncthreads();
    }
    if (tid == 0) {
        const double denom = (double)BS_TOT * (double)D2;   // 16777216
        out[(size_t)BS_TOT * VOCAB]     = (float)(1.25 * rs[0] / denom);
        out[(size_t)BS_TOT * VOCAB + 1] = (float)(1.25 * rc[0] / denom);
    }
}

// ---------------- host ----------------
extern "C" void kernel_launch(void* const* d_in, const int* in_sizes, int n_in,
                              void* d_out, int out_size, void* d_ws, size_t ws_size,
                              hipStream_t stream) {
    const int*   x     = (const int*)  d_in[0];
    const float* mag   = (const float*)d_in[1];
    const float* phase = (const float*)d_in[2];
    const float* Wr    = (const float*)d_in[3];
    const float* Wi    = (const float*)d_in[4];
    const float* qw    = (const float*)d_in[5];
    const float* qb    = (const float*)d_in[6];
    const float* kw    = (const float*)d_in[7];
    const float* kb    = (const float*)d_in[8];
    const float* vw    = (const float*)d_in[9];
    const float* vb    = (const float*)d_in[10];
    const float* dec_w = (const float*)d_in[11];
    const float* dec_b = (const float*)d_in[12];
    const float* sym   = (const float*)d_in[13];
    const float* con   = (const float*)d_in[14];
    float* out = (float*)d_out;

    // workspace layout (floats); total ~44 MB
    float* ws     = (float*)d_ws;
    float* bufA   = ws;                          // 256*1024
    float* bufB   = bufA + NTOK * D2;            // 256*1024
    float* Kmem   = bufB + NTOK * D2;            // 6*256*512
    float* Vmem   = Kmem + NDEPTH * NTOK * DD;   // 6*256*1024
    float* rows   = Vmem + NDEPTH * NTOK * D2;   // 256*256
    float* CW     = rows + NTOK * VOCAB;         // 1024*1024
    float* qwT    = CW + D2 * D2;                // 1024*512
    float* KVT    = qwT + D2 * DD;               // 1024*1536
    float* symT   = KVT + D2 * 1536;             // 1024*512
    float* decT   = symT + D2 * NSYM;            // 1024*256
    float* conT   = decT + D2 * VOCAB;           // 1024*64
    float* cellP  = conT + D2 * NCON;            // 4*256*1024
    float* QP     = cellP + SPLIT * NTOK * D2;   // 4*256*512
    float* symP   = QP + SPLIT * NTOK * DD;      // 4*256*512
    float* kvP    = symP + SPLIT * NTOK * NSYM;  // 4*256*1536
    float* decP   = kvP + SPLIT * NTOK * 1536;   // 4*256*256
    float* snorm  = decP + SPLIT * NTOK * VOCAB; // 512
    float* conf   = snorm + NSYM;                // 256
    float* symErr = conf + NTOK;                 // 256
    float* conErr = symErr + NTOK;               // 256
    int*   hist   = (int*)(conErr + NTOK);       // 256

    dim3 tb(32, 8);
    buildcw_kernel<<<dim3(16, 16), tb, 0, stream>>>(Wr, Wi, CW);
    transposeS_kernel<<<dim3(32, 16), tb, 0, stream>>>(qw,    qwT,       DD,    D2, DD);
    transposeS_kernel<<<dim3(32, 16), tb, 0, stream>>>(kw,    KVT,       DD,    D2, 1536);
    transposeS_kernel<<<dim3(32, 32), tb, 0, stream>>>(vw,    KVT + DD,  D2,    D2, 1536);
    transposeS_kernel<<<dim3(32, 16), tb, 0, stream>>>(sym,   symT,      NSYM,  D2, NSYM);
    transposeS_kernel<<<dim3(32,  8), tb, 0, stream>>>(dec_w, decT,      VOCAB, D2, VOCAB);
    transposeS_kernel<<<dim3(32,  2), tb, 0, stream>>>(con,   conT,      NCON,  D2, NCON);

    zero_kernel<<<1, 256, 0, stream>>>(symErr, conErr, hist);
    hist_kernel<<<BS_TOT / 256, 256, 0, stream>>>(x, hist);
    symnorm_kernel<<<NSYM, 256, 0, stream>>>(sym, snorm);
    embed_kernel<<<NTOK, 512, 0, stream>>>(mag, phase, bufA);

    float* cur = bufA;
    float* oth = bufB;
    for (int d = 0; d < NDEPTH; ++d) {
        gemm64_kernel<<<dim3(16, 4, SPLIT), 256, 0, stream>>>(CW, cur, cellP, D2);
        cellepi_kernel<<<dim3(2, 256), 256, 0, stream>>>(cellP, oth);
        { float* t = cur; cur = oth; oth = t; }
        if (d > 0) {
            gemm64_kernel<<<dim3(8, 4, SPLIT), 256, 0, stream>>>(qwT, cur, QP, DD);
            attend_kernel<<<NTOK, 256, 0, stream>>>(cur, QP, qb, Kmem, Vmem, conf, d);
        }
        gemm64_kernel<<<dim3(8, 4, SPLIT), 256, 0, stream>>>(symT, cur, symP, NSYM);
        finish_kernel<<<NTOK, 512, 0, stream>>>(cur, sym, snorm, con, conT, symP,
                                                conf, symErr, conErr);
        gemm64_kernel<<<dim3(24, 4, SPLIT), 256, 0, stream>>>(KVT, cur, kvP, 1536);
        kvcomb_kernel<<<dim3(6, 256), 256, 0, stream>>>(kvP, kb, vb,
                                                        Kmem + (size_t)d * NTOK * DD,
                                                        Vmem + (size_t)d * NTOK * D2);
    }
    for (int l = 0; l < NLOOK; ++l) {
        gemm64_kernel<<<dim3(16, 4, SPLIT), 256, 0, stream>>>(CW, cur, cellP, D2);
        cellepi_kernel<<<dim3(2, 256), 256, 0, stream>>>(cellP, oth);
        { float* t = cur; cur = oth; oth = t; }
    }
    gemm64_kernel<<<dim3(4, 4, SPLIT), 256, 0, stream>>>(decT, cur, decP, VOCAB);
    deccomb_kernel<<<256, 256, 0, stream>>>(decP, dec_b, rows);
    scatter_kernel<<<BS_TOT / 4, 256, 0, stream>>>(x, rows, out);
    loss_kernel<<<1, 256, 0, stream>>>(hist, symErr, conErr, out);
}